// Round 6
// baseline (284.697 us; speedup 1.0000x reference)
//
#include <hip/hip_runtime.h>
#include <math.h>

#define H128 128
#define NBLK 64      // blocks for the binning passes
#define BKT 256      // dsts per bucket
#define MAXNB 512    // max buckets supported (N <= 131072)

typedef short bf16x8 __attribute__((ext_vector_type(8)));
typedef unsigned short u16x8 __attribute__((ext_vector_type(8)));
typedef float f32x4 __attribute__((ext_vector_type(4)));

// ---------- helpers ----------
__device__ __forceinline__ unsigned long long enc64(double d) {
    unsigned long long b = (unsigned long long)__double_as_longlong(d);
    return (b & 0x8000000000000000ULL) ? ~b : (b | 0x8000000000000000ULL);
}

__device__ __forceinline__ unsigned short f2bf(float f) {   // fp32 -> bf16 RNE
    unsigned u = __float_as_uint(f);
    return (unsigned short)((u + 0x7FFFu + ((u >> 16) & 1u)) >> 16);
}

__device__ __forceinline__ float bf2f(unsigned short b) {
    return __uint_as_float((unsigned)b << 16);
}

// ---------- K1: fused [logits (fp64) + x->bf16]  |  [bucket histogram] ----------
// Blocks [0, PB): prep rows.  Blocks [PB, PB+NBLK): LDS histogram of dst buckets.
__global__ __launch_bounds__(256) void k_front(const float* __restrict__ x,
        const float* __restrict__ wl, const float* __restrict__ bl,
        unsigned short* __restrict__ xb, double* __restrict__ logits,
        const int* __restrict__ dsts, int* __restrict__ histg,
        int N, int E, int NB, int PB) {
    __shared__ int h[MAXNB];
    if ((int)blockIdx.x < PB) {
        int wave = (int)(blockIdx.x * 4 + (threadIdx.x >> 6));
        int lane = threadIdx.x & 63;
        if (wave >= N) return;
        const float2 v = *reinterpret_cast<const float2*>(x + (size_t)wave * H128 + lane * 2);
        const float2 w = *reinterpret_cast<const float2*>(wl + lane * 2);
        unsigned p = (unsigned)f2bf(v.x) | ((unsigned)f2bf(v.y) << 16);
        *reinterpret_cast<unsigned*>(xb + (size_t)wave * H128 + lane * 2) = p;
        double s = (double)v.x * (double)w.x + (double)v.y * (double)w.y;
#pragma unroll
        for (int off = 32; off > 0; off >>= 1) s += __shfl_down(s, off);
        if (lane == 0) logits[wave] = s + (double)bl[0];
    } else {
        int bid = blockIdx.x - PB;
        for (int i = threadIdx.x; i < NB; i += 256) h[i] = 0;
        __syncthreads();
        int per = (E + NBLK - 1) / NBLK;
        int s = bid * per;
        int e = min(E, s + per);
        for (int j = s + threadIdx.x; j < e; j += 256)
            atomicAdd(&h[dsts[j] >> 8], 1);
        __syncthreads();
        for (int i = threadIdx.x; i < NB; i += 256)
            histg[i * NBLK + bid] = h[i];   // bucket-major
    }
}

// ---------- binning pass 2: bucket totals + scan + per-(bucket,block) cursors ----------
__global__ __launch_bounds__(MAXNB) void k_offsets(const int* __restrict__ histg,
        int* __restrict__ bstart, int* __restrict__ base, int NB) {
    __shared__ int sm[MAXNB];
    int t = threadIdx.x;
    int tot = 0;
    if (t < NB) {
        const int4* p = reinterpret_cast<const int4*>(histg + t * NBLK);
#pragma unroll
        for (int i = 0; i < NBLK / 4; ++i) { int4 v = p[i]; tot += v.x + v.y + v.z + v.w; }
    }
    sm[t] = tot;
    __syncthreads();
    for (int o = 1; o < MAXNB; o <<= 1) {
        int add = (t >= o) ? sm[t - o] : 0;
        __syncthreads();
        sm[t] += add;
        __syncthreads();
    }
    if (t == 0) bstart[0] = 0;
    if (t < NB) {
        bstart[t + 1] = sm[t];
        // per-(bucket,block) write cursors
        int acc = sm[t] - tot;   // exclusive start of bucket t
        const int4* hp = reinterpret_cast<const int4*>(histg + t * NBLK);
        int4* bp = reinterpret_cast<int4*>(base + t * NBLK);
#pragma unroll
        for (int i = 0; i < NBLK / 4; ++i) {
            int4 hv = hp[i];
            int4 o;
            o.x = acc; acc += hv.x;
            o.y = acc; acc += hv.y;
            o.z = acc; acc += hv.z;
            o.w = acc; acc += hv.w;
            bp[i] = o;
        }
    }
}

// ---------- binning pass 3: scatter edges into bucket-segmented runs (packed u32) ----------
__global__ __launch_bounds__(256) void k_binscatter(const int* __restrict__ srcs,
        const int* __restrict__ dsts, const int* __restrict__ base,
        unsigned* __restrict__ binned, int E, int NB) {
    __shared__ int cur[MAXNB];
    for (int i = threadIdx.x; i < NB; i += 256)
        cur[i] = base[i * NBLK + blockIdx.x];
    __syncthreads();
    int per = (E + NBLK - 1) / NBLK;
    int s = blockIdx.x * per;
    int e = min(E, s + per);
    for (int j = s + threadIdx.x; j < e; j += 256) {
        int d = dsts[j], r = srcs[j];
        int pos = atomicAdd(&cur[d >> 8], 1);
        binned[pos] = ((unsigned)(d & (BKT - 1)) << 24) | (unsigned)r;
    }
}

// ---------- binning pass 4: per-bucket local CSR (sequential global writes) ----------
__global__ __launch_bounds__(BKT) void k_localize(const unsigned* __restrict__ binned,
        const int* __restrict__ bstart, int* __restrict__ starts,
        int* __restrict__ csr, int N, int E, int NB) {
    __shared__ int deg[BKT];
    __shared__ int sm[BKT];
    __shared__ int cur[BKT];
    int b = blockIdx.x, t = threadIdx.x;
    int s0 = bstart[b], s1 = bstart[b + 1];
    deg[t] = 0;
    __syncthreads();
    for (int j = s0 + t; j < s1; j += BKT)
        atomicAdd(&deg[binned[j] >> 24], 1);
    __syncthreads();
    int v = deg[t];
    sm[t] = v;
    __syncthreads();
    for (int o = 1; o < BKT; o <<= 1) {
        int add = (t >= o) ? sm[t - o] : 0;
        __syncthreads();
        sm[t] += add;
        __syncthreads();
    }
    int excl = sm[t] - v;
    cur[t] = excl;
    int d = b * BKT + t;
    if (d < N) starts[d] = s0 + excl;
    if (b == NB - 1 && t == 0) starts[N] = E;
    __syncthreads();
    for (int j = s0 + t; j < s1; j += BKT) {
        unsigned p = binned[j];
        int pos = atomicAdd(&cur[p >> 24], 1);
        csr[s0 + pos] = (int)(p & 0xFFFFFFu);
    }
}

// ---------- K4: bf16 gather-aggregate mean + lane-parallel leader election ----------
// 16 lanes per dst, ushort8 (16B) per lane, 8-deep row pipeline, fp32 accum.
__global__ __launch_bounds__(256) void k_aggregate(const int* __restrict__ starts,
        const int* __restrict__ csr, const unsigned short* __restrict__ xb,
        const double* __restrict__ logits, unsigned short* __restrict__ meanb,
        int* __restrict__ leader, int N) {
    int d = blockIdx.x * 16 + (threadIdx.x >> 4);
    int lane = threadIdx.x & 15;
    if (d >= N) return;
    int s = starts[d], e = starts[d + 1];
    const unsigned short* xp = xb + lane * 8;
    float a[8];
#pragma unroll
    for (int i = 0; i < 8; ++i) a[i] = 0.f;

    unsigned long long best; int bsrc;
    if (lane == 0) { best = enc64(logits[d]); bsrc = d; }   // self-loop seed
    else { best = 0ULL; bsrc = -1; }

    int j = s;
    for (; j + 8 <= e; j += 8) {
        int r[8];
#pragma unroll
        for (int q = 0; q < 8; ++q) r[q] = csr[j + q];
        u16x8 v[8];
#pragma unroll
        for (int q = 0; q < 8; ++q)
            v[q] = *reinterpret_cast<const u16x8*>(xp + (size_t)r[q] * H128);
#pragma unroll
        for (int i = 0; i < 8; ++i)
            a[i] += ((bf2f(v[0][i]) + bf2f(v[1][i])) + (bf2f(v[2][i]) + bf2f(v[3][i])))
                  + ((bf2f(v[4][i]) + bf2f(v[5][i])) + (bf2f(v[6][i]) + bf2f(v[7][i])));
        if (lane < 8) {   // 8 lanes split the election for this batch
            int rr = r[lane];
            unsigned long long lg = enc64(logits[rr]);
            if (lg > best || (lg == best && rr > bsrc)) { best = lg; bsrc = rr; }
        }
    }
    for (; j + 2 <= e; j += 2) {
        int r0 = csr[j], r1 = csr[j + 1];
        u16x8 v0 = *reinterpret_cast<const u16x8*>(xp + (size_t)r0 * H128);
        u16x8 v1 = *reinterpret_cast<const u16x8*>(xp + (size_t)r1 * H128);
#pragma unroll
        for (int i = 0; i < 8; ++i) a[i] += bf2f(v0[i]) + bf2f(v1[i]);
        if (lane == 0) {
            unsigned long long lg = enc64(logits[r0]);
            if (lg > best || (lg == best && r0 > bsrc)) { best = lg; bsrc = r0; }
        } else if (lane == 1) {
            unsigned long long lg = enc64(logits[r1]);
            if (lg > best || (lg == best && r1 > bsrc)) { best = lg; bsrc = r1; }
        }
    }
    if (j < e) {
        int r0 = csr[j];
        u16x8 v0 = *reinterpret_cast<const u16x8*>(xp + (size_t)r0 * H128);
#pragma unroll
        for (int i = 0; i < 8; ++i) a[i] += bf2f(v0[i]);
        if (lane == 0) {
            unsigned long long lg = enc64(logits[r0]);
            if (lg > best || (lg == best && r0 > bsrc)) { best = lg; bsrc = r0; }
        }
    }
    // combine election across 16 lanes
#pragma unroll
    for (int o = 8; o > 0; o >>= 1) {
        unsigned long long ob = __shfl_xor(best, o);
        int os = __shfl_xor(bsrc, o);
        if (ob > best || (ob == best && os > bsrc)) { best = ob; bsrc = os; }
    }
    if (lane == 0) leader[d] = bsrc;
    float inv = 1.0f / fmaxf((float)(e - s), 1.0f);
    u16x8 mo;
#pragma unroll
    for (int i = 0; i < 8; ++i) mo[i] = f2bf(a[i] * inv);
    *reinterpret_cast<u16x8*>(meanb + (size_t)d * H128 + lane * 8) = mo;
}

// ---------- K5/K6: MFMA GEMM: out[n,:] = act(A[rowsel(n),:] @ W + bias) ----------
__global__ __launch_bounds__(256, 2) void k_gemm_mfma(
        const unsigned short* __restrict__ A, const float* __restrict__ W,
        const float* __restrict__ bias, const int* __restrict__ leader,
        float* __restrict__ outf, unsigned short* __restrict__ outb,
        int N, int dogelu) {
    __shared__ unsigned short wlT[128][136];
    for (int i = threadIdx.x; i < 4096; i += 256) {
        int k = i >> 5;              // W row (k index)
        int n4 = (i & 31) * 4;       // 4 output channels
        float4 w = reinterpret_cast<const float4*>(W)[i];
        wlT[n4 + 0][k] = f2bf(w.x);
        wlT[n4 + 1][k] = f2bf(w.y);
        wlT[n4 + 2][k] = f2bf(w.z);
        wlT[n4 + 3][k] = f2bf(w.w);
    }
    __syncthreads();

    const int wid = threadIdx.x >> 6;
    const int lane = threadIdx.x & 63;
    const int row0 = blockIdx.x * 128 + wid * 32;
    const int kblk = (lane >> 4) * 8;

    int rows[2];
#pragma unroll
    for (int t = 0; t < 2; ++t) {
        int node = row0 + t * 16 + (lane & 15);
        int r = (node < N) ? node : (N - 1);
        if (leader) r = leader[r];
        rows[t] = r;
    }

    bf16x8 xf[2][4];
#pragma unroll
    for (int t = 0; t < 2; ++t)
#pragma unroll
        for (int s = 0; s < 4; ++s)
            xf[t][s] = *reinterpret_cast<const bf16x8*>(A + (size_t)rows[t] * H128 + s * 32 + kblk);

    f32x4 acc[2][8];
#pragma unroll
    for (int t = 0; t < 2; ++t)
#pragma unroll
        for (int cb = 0; cb < 8; ++cb)
#pragma unroll
            for (int j = 0; j < 4; ++j) acc[t][cb][j] = 0.0f;

#pragma unroll
    for (int cb = 0; cb < 8; ++cb) {
        const int ch = cb * 16 + (lane & 15);
#pragma unroll
        for (int s = 0; s < 4; ++s) {
            bf16x8 wf = *reinterpret_cast<bf16x8*>(&wlT[ch][s * 32 + kblk]);
            acc[0][cb] = __builtin_amdgcn_mfma_f32_16x16x32_bf16(wf, xf[0][s], acc[0][cb], 0, 0, 0);
            acc[1][cb] = __builtin_amdgcn_mfma_f32_16x16x32_bf16(wf, xf[1][s], acc[1][cb], 0, 0, 0);
        }
    }

    const int chq = (lane >> 4) * 4;
#pragma unroll
    for (int cb = 0; cb < 8; ++cb) {
        const float4 bv = *reinterpret_cast<const float4*>(&bias[cb * 16 + chq]);
#pragma unroll
        for (int t = 0; t < 2; ++t) {
            int node = row0 + t * 16 + (lane & 15);
            if (node >= N) continue;
            float o[4];
            o[0] = acc[t][cb][0] + bv.x;
            o[1] = acc[t][cb][1] + bv.y;
            o[2] = acc[t][cb][2] + bv.z;
            o[3] = acc[t][cb][3] + bv.w;
            if (dogelu) {
#pragma unroll
                for (int j = 0; j < 4; ++j)
                    o[j] = 0.5f * o[j] * (1.0f + erff(o[j] * 0.70710678118654752440f));
            }
            if (outb) {
                ushort4 ov;
                ov.x = f2bf(o[0]); ov.y = f2bf(o[1]); ov.z = f2bf(o[2]); ov.w = f2bf(o[3]);
                *reinterpret_cast<ushort4*>(outb + (size_t)node * H128 + cb * 16 + chq) = ov;
            } else {
                *reinterpret_cast<float4*>(outf + (size_t)node * H128 + cb * 16 + chq) =
                    make_float4(o[0], o[1], o[2], o[3]);
            }
        }
    }
}

extern "C" void kernel_launch(void* const* d_in, const int* in_sizes, int n_in,
                              void* d_out, int out_size, void* d_ws, size_t ws_size,
                              hipStream_t stream) {
    const float* x     = (const float*)d_in[0];
    const int*   ei    = (const int*)d_in[1];
    const float* wlead = (const float*)d_in[2];
    const float* blead = (const float*)d_in[3];
    const float* w1    = (const float*)d_in[4];
    const float* b1    = (const float*)d_in[5];
    const float* w2    = (const float*)d_in[6];
    const float* b2    = (const float*)d_in[7];
    float* out = (float*)d_out;

    const int N = in_sizes[0] / H128;
    const int E = in_sizes[1] / 2;
    const int NB = (N + BKT - 1) / BKT;
    const int PB = (N + 3) / 4;
    const int* srcs = ei;
    const int* dsts = ei + E;

    char* ws = (char*)d_ws;
    size_t off = 0;
    auto alloc = [&](size_t bytes) {
        void* p = ws + off;
        off = (off + bytes + 255) & ~(size_t)255;
        return p;
    };
    unsigned short* xb    = (unsigned short*)alloc((size_t)N * H128 * 2);
    unsigned short* meanb = (unsigned short*)alloc((size_t)N * H128 * 2);
    unsigned short* hbuf  = (unsigned short*)alloc((size_t)N * H128 * 2);
    double* logits = (double*)alloc((size_t)N * 8);
    int* leader = (int*)alloc((size_t)N * 4);
    int* starts = (int*)alloc((size_t)(N + 1) * 4);
    int* csr    = (int*)alloc((size_t)E * 4);
    unsigned* binned = (unsigned*)alloc((size_t)E * 4);
    int* histg  = (int*)alloc((size_t)NB * NBLK * 4);
    int* bstart = (int*)alloc((size_t)(NB + 1) * 4);
    int* base   = (int*)alloc((size_t)NB * NBLK * 4);

    // fused [logits + bf16 convert] | [bucket histogram]
    k_front<<<PB + NBLK, 256, 0, stream>>>(x, wlead, blead, xb, logits,
                                           dsts, histg, N, E, NB, PB);

    // bucket scan + cursors, then binned scatter, then per-bucket CSR
    k_offsets<<<1, MAXNB, 0, stream>>>(histg, bstart, base, NB);
    k_binscatter<<<NBLK, 256, 0, stream>>>(srcs, dsts, base, binned, E, NB);
    k_localize<<<NB, BKT, 0, stream>>>(binned, bstart, starts, csr, N, E, NB);

    // gather-aggregate mean (bf16) + leader election
    k_aggregate<<<(N + 15) / 16, 256, 0, stream>>>(starts, csr, xb, logits, meanb, leader, N);

    // MLP: GEMM1 (mean -> h, gelu, bf16), GEMM2 fused with leader-gather (-> out fp32)
    k_gemm_mfma<<<(N + 127) / 128, 256, 0, stream>>>(meanb, w1, b1, nullptr, nullptr, hbuf, N, 1);
    k_gemm_mfma<<<(N + 127) / 128, 256, 0, stream>>>(hbuf, w2, b2, leader, out, nullptr, N, 0);
}

// Round 7
// 276.213 us; speedup vs baseline: 1.0307x; 1.0307x over previous
//
#include <hip/hip_runtime.h>
#include <math.h>

#define H128 128
#define NBLK 256     // blocks for the binning passes
#define BKT 256      // dsts per bucket
#define MAXNB 512    // max buckets supported (N <= 131072)

typedef short bf16x8 __attribute__((ext_vector_type(8)));
typedef unsigned short u16x8 __attribute__((ext_vector_type(8)));
typedef float f32x4 __attribute__((ext_vector_type(4)));

// ---------- helpers ----------
__device__ __forceinline__ unsigned long long enc64(double d) {
    unsigned long long b = (unsigned long long)__double_as_longlong(d);
    return (b & 0x8000000000000000ULL) ? ~b : (b | 0x8000000000000000ULL);
}

__device__ __forceinline__ unsigned short f2bf(float f) {   // fp32 -> bf16 RNE
    unsigned u = __float_as_uint(f);
    return (unsigned short)((u + 0x7FFFu + ((u >> 16) & 1u)) >> 16);
}

__device__ __forceinline__ float bf2f(unsigned short b) {
    return __uint_as_float((unsigned)b << 16);
}

// ---------- K1: fused [bucket histogram (blocks 0..NBLK)] | [logits+x->bf16] ----------
// Histogram blocks FIRST in the grid so they overlap the BW-bound prep blocks
// instead of running as a serial tail (round-6 lesson).
__global__ __launch_bounds__(256) void k_front(const float* __restrict__ x,
        const float* __restrict__ wl, const float* __restrict__ bl,
        unsigned short* __restrict__ xb, double* __restrict__ logits,
        const int* __restrict__ dsts, int* __restrict__ histg,
        int N, int E, int NB) {
    __shared__ int h[MAXNB];
    if ((int)blockIdx.x < NBLK) {
        int bid = blockIdx.x;
        for (int i = threadIdx.x; i < NB; i += 256) h[i] = 0;
        __syncthreads();
        int per = (E + NBLK - 1) / NBLK;
        int s = bid * per;
        int e = min(E, s + per);
        for (int j = s + threadIdx.x; j < e; j += 256)
            atomicAdd(&h[dsts[j] >> 8], 1);
        __syncthreads();
        for (int i = threadIdx.x; i < NB; i += 256)
            histg[i * NBLK + bid] = h[i];   // bucket-major
    } else {
        int wave = (int)((blockIdx.x - NBLK) * 4 + (threadIdx.x >> 6));
        int lane = threadIdx.x & 63;
        if (wave >= N) return;
        const float2 v = *reinterpret_cast<const float2*>(x + (size_t)wave * H128 + lane * 2);
        const float2 w = *reinterpret_cast<const float2*>(wl + lane * 2);
        unsigned p = (unsigned)f2bf(v.x) | ((unsigned)f2bf(v.y) << 16);
        *reinterpret_cast<unsigned*>(xb + (size_t)wave * H128 + lane * 2) = p;
        double s = (double)v.x * (double)w.x + (double)v.y * (double)w.y;
#pragma unroll
        for (int off = 32; off > 0; off >>= 1) s += __shfl_down(s, off);
        if (lane == 0) logits[wave] = s + (double)bl[0];
    }
}

// ---------- pass 2: bucket totals + scan + per-(bucket,block) cursors ----------
__global__ __launch_bounds__(MAXNB) void k_offsets(const int* __restrict__ histg,
        int* __restrict__ bstart, int* __restrict__ base, int NB) {
    __shared__ int sm[MAXNB];
    int t = threadIdx.x;
    int tot = 0;
    if (t < NB) {
        const int4* p = reinterpret_cast<const int4*>(histg + t * NBLK);
#pragma unroll 8
        for (int i = 0; i < NBLK / 4; ++i) { int4 v = p[i]; tot += v.x + v.y + v.z + v.w; }
    }
    sm[t] = tot;
    __syncthreads();
    for (int o = 1; o < MAXNB; o <<= 1) {
        int add = (t >= o) ? sm[t - o] : 0;
        __syncthreads();
        sm[t] += add;
        __syncthreads();
    }
    if (t == 0) bstart[0] = 0;
    if (t < NB) {
        bstart[t + 1] = sm[t];
        int acc = sm[t] - tot;   // exclusive start of bucket t
        const int4* hp = reinterpret_cast<const int4*>(histg + t * NBLK);
        int4* bp = reinterpret_cast<int4*>(base + t * NBLK);
#pragma unroll 8
        for (int i = 0; i < NBLK / 4; ++i) {
            int4 hv = hp[i];
            int4 o;
            o.x = acc; acc += hv.x;
            o.y = acc; acc += hv.y;
            o.z = acc; acc += hv.z;
            o.w = acc; acc += hv.w;
            bp[i] = o;
        }
    }
}

// ---------- pass 3: scatter edges into bucket-segmented runs (packed u32) ----------
__global__ __launch_bounds__(256) void k_binscatter(const int* __restrict__ srcs,
        const int* __restrict__ dsts, const int* __restrict__ base,
        unsigned* __restrict__ binned, int E, int NB) {
    __shared__ int cur[MAXNB];
    for (int i = threadIdx.x; i < NB; i += 256)
        cur[i] = base[i * NBLK + blockIdx.x];
    __syncthreads();
    int per = (E + NBLK - 1) / NBLK;
    int s = blockIdx.x * per;
    int e = min(E, s + per);
    for (int j = s + threadIdx.x; j < e; j += 256) {
        int d = dsts[j], r = srcs[j];
        int pos = atomicAdd(&cur[d >> 8], 1);
        binned[pos] = ((unsigned)(d & (BKT - 1)) << 24) | (unsigned)r;
    }
}

// ---------- pass 4: per-bucket local CSR (sequential global writes) ----------
__global__ __launch_bounds__(BKT) void k_localize(const unsigned* __restrict__ binned,
        const int* __restrict__ bstart, int* __restrict__ starts,
        int* __restrict__ csr, int N, int E, int NB) {
    __shared__ int deg[BKT];
    __shared__ int sm[BKT];
    __shared__ int cur[BKT];
    int b = blockIdx.x, t = threadIdx.x;
    int s0 = bstart[b], s1 = bstart[b + 1];
    deg[t] = 0;
    __syncthreads();
    for (int j = s0 + t; j < s1; j += BKT)
        atomicAdd(&deg[binned[j] >> 24], 1);
    __syncthreads();
    int v = deg[t];
    sm[t] = v;
    __syncthreads();
    for (int o = 1; o < BKT; o <<= 1) {
        int add = (t >= o) ? sm[t - o] : 0;
        __syncthreads();
        sm[t] += add;
        __syncthreads();
    }
    int excl = sm[t] - v;
    cur[t] = excl;
    int d = b * BKT + t;
    if (d < N) starts[d] = s0 + excl;
    if (b == NB - 1 && t == 0) starts[N] = E;
    __syncthreads();
    for (int j = s0 + t; j < s1; j += BKT) {
        unsigned p = binned[j];
        int pos = atomicAdd(&cur[p >> 24], 1);
        csr[s0 + pos] = (int)(p & 0xFFFFFFu);
    }
}

// ---------- K4: bf16 gather-aggregate mean + lane-parallel leader election ----------
// 16 lanes per dst, ushort8 (16B) per lane, 4-deep row pipeline, fp32 accum.
// (r5 version: 28 VGPR, occupancy ~65% — 8-deep regressed via occupancy, r6.)
__global__ __launch_bounds__(256) void k_aggregate(const int* __restrict__ starts,
        const int* __restrict__ csr, const unsigned short* __restrict__ xb,
        const double* __restrict__ logits, unsigned short* __restrict__ meanb,
        int* __restrict__ leader, int N) {
    int d = blockIdx.x * 16 + (threadIdx.x >> 4);
    int lane = threadIdx.x & 15;
    if (d >= N) return;
    int s = starts[d], e = starts[d + 1];
    const unsigned short* xp = xb + lane * 8;
    float a[8];
#pragma unroll
    for (int i = 0; i < 8; ++i) a[i] = 0.f;
    int j = s;
    for (; j + 4 <= e; j += 4) {
        int r0 = csr[j], r1 = csr[j + 1], r2 = csr[j + 2], r3 = csr[j + 3];
        u16x8 v0 = *reinterpret_cast<const u16x8*>(xp + (size_t)r0 * H128);
        u16x8 v1 = *reinterpret_cast<const u16x8*>(xp + (size_t)r1 * H128);
        u16x8 v2 = *reinterpret_cast<const u16x8*>(xp + (size_t)r2 * H128);
        u16x8 v3 = *reinterpret_cast<const u16x8*>(xp + (size_t)r3 * H128);
#pragma unroll
        for (int i = 0; i < 8; ++i)
            a[i] += (bf2f(v0[i]) + bf2f(v1[i])) + (bf2f(v2[i]) + bf2f(v3[i]));
    }
    for (; j < e; ++j) {
        int r0 = csr[j];
        u16x8 v0 = *reinterpret_cast<const u16x8*>(xp + (size_t)r0 * H128);
#pragma unroll
        for (int i = 0; i < 8; ++i) a[i] += bf2f(v0[i]);
    }
    // leader election: lane-parallel lexicographic max of (enc64(logit), src)
    unsigned long long best; int bsrc;
    if (lane == 0) { best = enc64(logits[d]); bsrc = d; }   // self-loop seed
    else { best = 0ULL; bsrc = -1; }
    for (int k2 = s + lane; k2 < e; k2 += 16) {
        int r = csr[k2];
        unsigned long long lg = enc64(logits[r]);
        if (lg > best || (lg == best && r > bsrc)) { best = lg; bsrc = r; }
    }
#pragma unroll
    for (int o = 8; o > 0; o >>= 1) {
        unsigned long long ob = __shfl_xor(best, o);
        int os = __shfl_xor(bsrc, o);
        if (ob > best || (ob == best && os > bsrc)) { best = ob; bsrc = os; }
    }
    if (lane == 0) leader[d] = bsrc;
    float inv = 1.0f / fmaxf((float)(e - s), 1.0f);
    u16x8 mo;
#pragma unroll
    for (int i = 0; i < 8; ++i) mo[i] = f2bf(a[i] * inv);
    *reinterpret_cast<u16x8*>(meanb + (size_t)d * H128 + lane * 8) = mo;
}

// ---------- K5/K6: MFMA GEMM: out[n,:] = act(A[rowsel(n),:] @ W + bias) ----------
__global__ __launch_bounds__(256, 2) void k_gemm_mfma(
        const unsigned short* __restrict__ A, const float* __restrict__ W,
        const float* __restrict__ bias, const int* __restrict__ leader,
        float* __restrict__ outf, unsigned short* __restrict__ outb,
        int N, int dogelu) {
    __shared__ unsigned short wlT[128][136];
    for (int i = threadIdx.x; i < 4096; i += 256) {
        int k = i >> 5;              // W row (k index)
        int n4 = (i & 31) * 4;       // 4 output channels
        float4 w = reinterpret_cast<const float4*>(W)[i];
        wlT[n4 + 0][k] = f2bf(w.x);
        wlT[n4 + 1][k] = f2bf(w.y);
        wlT[n4 + 2][k] = f2bf(w.z);
        wlT[n4 + 3][k] = f2bf(w.w);
    }
    __syncthreads();

    const int wid = threadIdx.x >> 6;
    const int lane = threadIdx.x & 63;
    const int row0 = blockIdx.x * 128 + wid * 32;
    const int kblk = (lane >> 4) * 8;

    int rows[2];
#pragma unroll
    for (int t = 0; t < 2; ++t) {
        int node = row0 + t * 16 + (lane & 15);
        int r = (node < N) ? node : (N - 1);
        if (leader) r = leader[r];
        rows[t] = r;
    }

    bf16x8 xf[2][4];
#pragma unroll
    for (int t = 0; t < 2; ++t)
#pragma unroll
        for (int s = 0; s < 4; ++s)
            xf[t][s] = *reinterpret_cast<const bf16x8*>(A + (size_t)rows[t] * H128 + s * 32 + kblk);

    f32x4 acc[2][8];
#pragma unroll
    for (int t = 0; t < 2; ++t)
#pragma unroll
        for (int cb = 0; cb < 8; ++cb)
#pragma unroll
            for (int j = 0; j < 4; ++j) acc[t][cb][j] = 0.0f;

#pragma unroll
    for (int cb = 0; cb < 8; ++cb) {
        const int ch = cb * 16 + (lane & 15);
#pragma unroll
        for (int s = 0; s < 4; ++s) {
            bf16x8 wf = *reinterpret_cast<bf16x8*>(&wlT[ch][s * 32 + kblk]);
            acc[0][cb] = __builtin_amdgcn_mfma_f32_16x16x32_bf16(wf, xf[0][s], acc[0][cb], 0, 0, 0);
            acc[1][cb] = __builtin_amdgcn_mfma_f32_16x16x32_bf16(wf, xf[1][s], acc[1][cb], 0, 0, 0);
        }
    }

    const int chq = (lane >> 4) * 4;
#pragma unroll
    for (int cb = 0; cb < 8; ++cb) {
        const float4 bv = *reinterpret_cast<const float4*>(&bias[cb * 16 + chq]);
#pragma unroll
        for (int t = 0; t < 2; ++t) {
            int node = row0 + t * 16 + (lane & 15);
            if (node >= N) continue;
            float o[4];
            o[0] = acc[t][cb][0] + bv.x;
            o[1] = acc[t][cb][1] + bv.y;
            o[2] = acc[t][cb][2] + bv.z;
            o[3] = acc[t][cb][3] + bv.w;
            if (dogelu) {
#pragma unroll
                for (int j = 0; j < 4; ++j)
                    o[j] = 0.5f * o[j] * (1.0f + erff(o[j] * 0.70710678118654752440f));
            }
            if (outb) {
                ushort4 ov;
                ov.x = f2bf(o[0]); ov.y = f2bf(o[1]); ov.z = f2bf(o[2]); ov.w = f2bf(o[3]);
                *reinterpret_cast<ushort4*>(outb + (size_t)node * H128 + cb * 16 + chq) = ov;
            } else {
                *reinterpret_cast<float4*>(outf + (size_t)node * H128 + cb * 16 + chq) =
                    make_float4(o[0], o[1], o[2], o[3]);
            }
        }
    }
}

extern "C" void kernel_launch(void* const* d_in, const int* in_sizes, int n_in,
                              void* d_out, int out_size, void* d_ws, size_t ws_size,
                              hipStream_t stream) {
    const float* x     = (const float*)d_in[0];
    const int*   ei    = (const int*)d_in[1];
    const float* wlead = (const float*)d_in[2];
    const float* blead = (const float*)d_in[3];
    const float* w1    = (const float*)d_in[4];
    const float* b1    = (const float*)d_in[5];
    const float* w2    = (const float*)d_in[6];
    const float* b2    = (const float*)d_in[7];
    float* out = (float*)d_out;

    const int N = in_sizes[0] / H128;
    const int E = in_sizes[1] / 2;
    const int NB = (N + BKT - 1) / BKT;
    const int PB = (N + 3) / 4;
    const int* srcs = ei;
    const int* dsts = ei + E;

    char* ws = (char*)d_ws;
    size_t off = 0;
    auto alloc = [&](size_t bytes) {
        void* p = ws + off;
        off = (off + bytes + 255) & ~(size_t)255;
        return p;
    };
    unsigned short* xb    = (unsigned short*)alloc((size_t)N * H128 * 2);
    unsigned short* meanb = (unsigned short*)alloc((size_t)N * H128 * 2);
    unsigned short* hbuf  = (unsigned short*)alloc((size_t)N * H128 * 2);
    double* logits = (double*)alloc((size_t)N * 8);
    int* leader = (int*)alloc((size_t)N * 4);
    int* starts = (int*)alloc((size_t)(N + 1) * 4);
    int* csr    = (int*)alloc((size_t)E * 4);
    unsigned* binned = (unsigned*)alloc((size_t)E * 4);
    int* histg  = (int*)alloc((size_t)NB * NBLK * 4);
    int* bstart = (int*)alloc((size_t)(NB + 1) * 4);
    int* base   = (int*)alloc((size_t)NB * NBLK * 4);

    // fused [bucket histogram first] | [logits + bf16 convert]
    k_front<<<NBLK + PB, 256, 0, stream>>>(x, wlead, blead, xb, logits,
                                           dsts, histg, N, E, NB);

    // bucket scan + cursors, then binned scatter, then per-bucket CSR
    k_offsets<<<1, MAXNB, 0, stream>>>(histg, bstart, base, NB);
    k_binscatter<<<NBLK, 256, 0, stream>>>(srcs, dsts, base, binned, E, NB);
    k_localize<<<NB, BKT, 0, stream>>>(binned, bstart, starts, csr, N, E, NB);

    // gather-aggregate mean (bf16) + leader election
    k_aggregate<<<(N + 15) / 16, 256, 0, stream>>>(starts, csr, xb, logits, meanb, leader, N);

    // MLP: GEMM1 (mean -> h, gelu, bf16), GEMM2 fused with leader-gather (-> out fp32)
    k_gemm_mfma<<<(N + 127) / 128, 256, 0, stream>>>(meanb, w1, b1, nullptr, nullptr, hbuf, N, 1);
    k_gemm_mfma<<<(N + 127) / 128, 256, 0, stream>>>(hbuf, w2, b2, leader, out, nullptr, N, 0);
}

// Round 8
// 255.674 us; speedup vs baseline: 1.1135x; 1.0803x over previous
//
#include <hip/hip_runtime.h>
#include <math.h>

#define H128 128
#define NBLK 256     // blocks for the binning passes
#define BKT 256      // dsts per bucket
#define MAXNB 512    // max buckets supported (N <= 131072)

typedef short bf16x8 __attribute__((ext_vector_type(8)));
typedef unsigned short u16x8 __attribute__((ext_vector_type(8)));
typedef float f32x4 __attribute__((ext_vector_type(4)));

// ---------- helpers ----------
__device__ __forceinline__ unsigned long long enc64(double d) {
    unsigned long long b = (unsigned long long)__double_as_longlong(d);
    return (b & 0x8000000000000000ULL) ? ~b : (b | 0x8000000000000000ULL);
}

__device__ __forceinline__ unsigned short f2bf(float f) {   // fp32 -> bf16 RNE
    unsigned u = __float_as_uint(f);
    return (unsigned short)((u + 0x7FFFu + ((u >> 16) & 1u)) >> 16);
}

__device__ __forceinline__ float bf2f(unsigned short b) {
    return __uint_as_float((unsigned)b << 16);
}

// ---------- K1: fused [bucket hist | prep (4 rows/wave ILP) | W transpose] ----------
// Grid: [0,NBLK) histogram; [NBLK, NBLK+PB) prep; last 2 blocks: W1/W2 ->
// bf16 chunk-major gwT[c][ch][8] (c = k/8), enabling conflict-free GEMM staging.
__global__ __launch_bounds__(256) void k_front(const float* __restrict__ x,
        const float* __restrict__ wl, const float* __restrict__ bl,
        unsigned short* __restrict__ xb, double* __restrict__ logits,
        const int* __restrict__ dsts, int* __restrict__ histg,
        const float* __restrict__ w1, const float* __restrict__ w2,
        unsigned short* __restrict__ gwT1, unsigned short* __restrict__ gwT2,
        int N, int E, int NB, int PB) {
    __shared__ int h[MAXNB];
    if ((int)blockIdx.x < NBLK) {
        int bid = blockIdx.x;
        for (int i = threadIdx.x; i < NB; i += 256) h[i] = 0;
        __syncthreads();
        int per = (E + NBLK - 1) / NBLK;
        int s = bid * per;
        int e = min(E, s + per);
        for (int j = s + threadIdx.x; j < e; j += 256)
            atomicAdd(&h[dsts[j] >> 8], 1);
        __syncthreads();
        for (int i = threadIdx.x; i < NB; i += 256)
            histg[i * NBLK + bid] = h[i];   // bucket-major
    } else if ((int)blockIdx.x < NBLK + PB) {
        int rb = (blockIdx.x - NBLK) * 16 + ((threadIdx.x >> 6) << 2);
        int lane = threadIdx.x & 63;
        const float2 w = *reinterpret_cast<const float2*>(wl + lane * 2);
        float2 v[4];
        int rr[4];
#pragma unroll
        for (int q = 0; q < 4; ++q) {
            int r = rb + q;
            rr[q] = (r < N) ? r : (N - 1);
            v[q] = *reinterpret_cast<const float2*>(x + (size_t)rr[q] * H128 + lane * 2);
        }
#pragma unroll
        for (int q = 0; q < 4; ++q) {
            if (rb + q < N) {
                unsigned p = (unsigned)f2bf(v[q].x) | ((unsigned)f2bf(v[q].y) << 16);
                *reinterpret_cast<unsigned*>(xb + (size_t)(rb + q) * H128 + lane * 2) = p;
            }
        }
        double s[4];
#pragma unroll
        for (int q = 0; q < 4; ++q)
            s[q] = (double)v[q].x * (double)w.x + (double)v[q].y * (double)w.y;
#pragma unroll
        for (int off = 32; off > 0; off >>= 1) {
#pragma unroll
            for (int q = 0; q < 4; ++q) s[q] += __shfl_down(s[q], off);
        }
        if (lane == 0) {
            double b = (double)bl[0];
#pragma unroll
            for (int q = 0; q < 4; ++q)
                if (rb + q < N) logits[rb + q] = s[q] + b;
        }
    } else {
        int which = blockIdx.x - NBLK - PB;           // 0 or 1
        const float* Wsrc = which ? w2 : w1;
        unsigned short* Wdst = which ? gwT2 : gwT1;
        for (int i = threadIdx.x; i < 4096; i += 256) {
            int k = i >> 5;
            int n4 = (i & 31) * 4;
            float4 wv = reinterpret_cast<const float4*>(Wsrc)[i];
            unsigned short* dp = Wdst + (size_t)(k >> 3) * 1024 + (k & 7);
            dp[(n4 + 0) * 8] = f2bf(wv.x);
            dp[(n4 + 1) * 8] = f2bf(wv.y);
            dp[(n4 + 2) * 8] = f2bf(wv.z);
            dp[(n4 + 3) * 8] = f2bf(wv.w);
        }
    }
}

// ---------- pass 2: bucket totals + scan + per-(bucket,block) cursors ----------
__global__ __launch_bounds__(MAXNB) void k_offsets(const int* __restrict__ histg,
        int* __restrict__ bstart, int* __restrict__ base, int NB) {
    __shared__ int sm[MAXNB];
    int t = threadIdx.x;
    int tot = 0;
    if (t < NB) {
        const int4* p = reinterpret_cast<const int4*>(histg + t * NBLK);
        for (int i = 0; i < NBLK / 4; ++i) { int4 v = p[i]; tot += v.x + v.y + v.z + v.w; }
    }
    sm[t] = tot;
    __syncthreads();
    for (int o = 1; o < MAXNB; o <<= 1) {
        int add = (t >= o) ? sm[t - o] : 0;
        __syncthreads();
        sm[t] += add;
        __syncthreads();
    }
    if (t == 0) bstart[0] = 0;
    if (t < NB) {
        bstart[t + 1] = sm[t];
        int acc = sm[t] - tot;   // exclusive start of bucket t
        const int4* hp = reinterpret_cast<const int4*>(histg + t * NBLK);
        int4* bp = reinterpret_cast<int4*>(base + t * NBLK);
        for (int i = 0; i < NBLK / 4; ++i) {
            int4 hv = hp[i];
            int4 o;
            o.x = acc; acc += hv.x;
            o.y = acc; acc += hv.y;
            o.z = acc; acc += hv.z;
            o.w = acc; acc += hv.w;
            bp[i] = o;
        }
    }
}

// ---------- pass 3: scatter edges into bucket-segmented runs (packed u32) ----------
__global__ __launch_bounds__(256) void k_binscatter(const int* __restrict__ srcs,
        const int* __restrict__ dsts, const int* __restrict__ base,
        unsigned* __restrict__ binned, int E, int NB) {
    __shared__ int cur[MAXNB];
    for (int i = threadIdx.x; i < NB; i += 256)
        cur[i] = base[i * NBLK + blockIdx.x];
    __syncthreads();
    int per = (E + NBLK - 1) / NBLK;
    int s = blockIdx.x * per;
    int e = min(E, s + per);
    for (int j = s + threadIdx.x; j < e; j += 256) {
        int d = dsts[j], r = srcs[j];
        int pos = atomicAdd(&cur[d >> 8], 1);
        binned[pos] = ((unsigned)(d & (BKT - 1)) << 24) | (unsigned)r;
    }
}

// ---------- pass 4: per-bucket local CSR (sequential global writes) ----------
__global__ __launch_bounds__(BKT) void k_localize(const unsigned* __restrict__ binned,
        const int* __restrict__ bstart, int* __restrict__ starts,
        int* __restrict__ csr, int N, int E, int NB) {
    __shared__ int deg[BKT];
    __shared__ int sm[BKT];
    __shared__ int cur[BKT];
    int b = blockIdx.x, t = threadIdx.x;
    int s0 = bstart[b], s1 = bstart[b + 1];
    deg[t] = 0;
    __syncthreads();
    for (int j = s0 + t; j < s1; j += BKT)
        atomicAdd(&deg[binned[j] >> 24], 1);
    __syncthreads();
    int v = deg[t];
    sm[t] = v;
    __syncthreads();
    for (int o = 1; o < BKT; o <<= 1) {
        int add = (t >= o) ? sm[t - o] : 0;
        __syncthreads();
        sm[t] += add;
        __syncthreads();
    }
    int excl = sm[t] - v;
    cur[t] = excl;
    int d = b * BKT + t;
    if (d < N) starts[d] = s0 + excl;
    if (b == NB - 1 && t == 0) starts[N] = E;
    __syncthreads();
    for (int j = s0 + t; j < s1; j += BKT) {
        unsigned p = binned[j];
        int pos = atomicAdd(&cur[p >> 24], 1);
        csr[s0 + pos] = (int)(p & 0xFFFFFFu);
    }
}

// ---------- K4: bf16 gather-aggregate mean + lane-parallel leader election ----------
// 16 lanes per dst, ushort8 (16B) per lane, 4-deep row pipeline, fp32 accum.
// (r5-verified config: 28 VGPR, occupancy ~65%; 8-deep regressed, r6.)
__global__ __launch_bounds__(256) void k_aggregate(const int* __restrict__ starts,
        const int* __restrict__ csr, const unsigned short* __restrict__ xb,
        const double* __restrict__ logits, unsigned short* __restrict__ meanb,
        int* __restrict__ leader, int N) {
    int d = blockIdx.x * 16 + (threadIdx.x >> 4);
    int lane = threadIdx.x & 15;
    if (d >= N) return;
    int s = starts[d], e = starts[d + 1];
    const unsigned short* xp = xb + lane * 8;
    float a[8];
#pragma unroll
    for (int i = 0; i < 8; ++i) a[i] = 0.f;
    int j = s;
    for (; j + 4 <= e; j += 4) {
        int r0 = csr[j], r1 = csr[j + 1], r2 = csr[j + 2], r3 = csr[j + 3];
        u16x8 v0 = *reinterpret_cast<const u16x8*>(xp + (size_t)r0 * H128);
        u16x8 v1 = *reinterpret_cast<const u16x8*>(xp + (size_t)r1 * H128);
        u16x8 v2 = *reinterpret_cast<const u16x8*>(xp + (size_t)r2 * H128);
        u16x8 v3 = *reinterpret_cast<const u16x8*>(xp + (size_t)r3 * H128);
#pragma unroll
        for (int i = 0; i < 8; ++i)
            a[i] += (bf2f(v0[i]) + bf2f(v1[i])) + (bf2f(v2[i]) + bf2f(v3[i]));
    }
    for (; j < e; ++j) {
        int r0 = csr[j];
        u16x8 v0 = *reinterpret_cast<const u16x8*>(xp + (size_t)r0 * H128);
#pragma unroll
        for (int i = 0; i < 8; ++i) a[i] += bf2f(v0[i]);
    }
    // leader election: lane-parallel lexicographic max of (enc64(logit), src)
    unsigned long long best; int bsrc;
    if (lane == 0) { best = enc64(logits[d]); bsrc = d; }   // self-loop seed
    else { best = 0ULL; bsrc = -1; }
    for (int k2 = s + lane; k2 < e; k2 += 16) {
        int r = csr[k2];
        unsigned long long lg = enc64(logits[r]);
        if (lg > best || (lg == best && r > bsrc)) { best = lg; bsrc = r; }
    }
#pragma unroll
    for (int o = 8; o > 0; o >>= 1) {
        unsigned long long ob = __shfl_xor(best, o);
        int os = __shfl_xor(bsrc, o);
        if (ob > best || (ob == best && os > bsrc)) { best = ob; bsrc = os; }
    }
    if (lane == 0) leader[d] = bsrc;
    float inv = 1.0f / fmaxf((float)(e - s), 1.0f);
    u16x8 mo;
#pragma unroll
    for (int i = 0; i < 8; ++i) mo[i] = f2bf(a[i] * inv);
    *reinterpret_cast<u16x8*>(meanb + (size_t)d * H128 + lane * 8) = mo;
}

// ---------- K5/K6: MFMA GEMM: out[n,:] = act(A[rowsel(n),:] @ W + bias) ----------
// W pre-transposed in global as bf16 chunk-major gwT[c][ch][8] (c = k/8):
// staging = linear float4 copy (bank-uniform, zero conflicts — r7's 6.4M
// conflicts were the in-kernel transpose writes). LDS exactly 32 KB -> 4 blocks/CU.
__global__ __launch_bounds__(256, 4) void k_gemm_mfma(
        const unsigned short* __restrict__ A, const unsigned short* __restrict__ gwT,
        const float* __restrict__ bias, const int* __restrict__ leader,
        float* __restrict__ outf, unsigned short* __restrict__ outb,
        int N, int dogelu) {
    __shared__ unsigned short wlT[16][128][8];   // [chunk c][channel][k in chunk]
    {
        const float4* src = reinterpret_cast<const float4*>(gwT);
        float4* dst = reinterpret_cast<float4*>(&wlT[0][0][0]);
#pragma unroll
        for (int i = 0; i < 8; ++i) dst[threadIdx.x + i * 256] = src[threadIdx.x + i * 256];
    }
    __syncthreads();

    const int wid = threadIdx.x >> 6;
    const int lane = threadIdx.x & 63;
    const int row0 = blockIdx.x * 128 + wid * 32;
    const int kblk = (lane >> 4) * 8;

    int rows[2];
#pragma unroll
    for (int t = 0; t < 2; ++t) {
        int node = row0 + t * 16 + (lane & 15);
        int r = (node < N) ? node : (N - 1);
        if (leader) r = leader[r];
        rows[t] = r;
    }

    bf16x8 xf[2][4];
#pragma unroll
    for (int t = 0; t < 2; ++t)
#pragma unroll
        for (int s = 0; s < 4; ++s)
            xf[t][s] = *reinterpret_cast<const bf16x8*>(A + (size_t)rows[t] * H128 + s * 32 + kblk);

    f32x4 acc[2][8];
#pragma unroll
    for (int t = 0; t < 2; ++t)
#pragma unroll
        for (int cb = 0; cb < 8; ++cb)
#pragma unroll
            for (int j = 0; j < 4; ++j) acc[t][cb][j] = 0.0f;

#pragma unroll
    for (int cb = 0; cb < 8; ++cb) {
        const int ch = cb * 16 + (lane & 15);
#pragma unroll
        for (int s = 0; s < 4; ++s) {
            bf16x8 wf = *reinterpret_cast<const bf16x8*>(&wlT[s * 4 + (lane >> 4)][ch][0]);
            acc[0][cb] = __builtin_amdgcn_mfma_f32_16x16x32_bf16(wf, xf[0][s], acc[0][cb], 0, 0, 0);
            acc[1][cb] = __builtin_amdgcn_mfma_f32_16x16x32_bf16(wf, xf[1][s], acc[1][cb], 0, 0, 0);
        }
    }

    const int chq = (lane >> 4) * 4;
#pragma unroll
    for (int cb = 0; cb < 8; ++cb) {
        const float4 bv = *reinterpret_cast<const float4*>(&bias[cb * 16 + chq]);
#pragma unroll
        for (int t = 0; t < 2; ++t) {
            int node = row0 + t * 16 + (lane & 15);
            if (node >= N) continue;
            float o[4];
            o[0] = acc[t][cb][0] + bv.x;
            o[1] = acc[t][cb][1] + bv.y;
            o[2] = acc[t][cb][2] + bv.z;
            o[3] = acc[t][cb][3] + bv.w;
            if (dogelu) {
#pragma unroll
                for (int j = 0; j < 4; ++j)
                    o[j] = 0.5f * o[j] * (1.0f + erff(o[j] * 0.70710678118654752440f));
            }
            if (outb) {
                ushort4 ov;
                ov.x = f2bf(o[0]); ov.y = f2bf(o[1]); ov.z = f2bf(o[2]); ov.w = f2bf(o[3]);
                *reinterpret_cast<ushort4*>(outb + (size_t)node * H128 + cb * 16 + chq) = ov;
            } else {
                *reinterpret_cast<float4*>(outf + (size_t)node * H128 + cb * 16 + chq) =
                    make_float4(o[0], o[1], o[2], o[3]);
            }
        }
    }
}

extern "C" void kernel_launch(void* const* d_in, const int* in_sizes, int n_in,
                              void* d_out, int out_size, void* d_ws, size_t ws_size,
                              hipStream_t stream) {
    const float* x     = (const float*)d_in[0];
    const int*   ei    = (const int*)d_in[1];
    const float* wlead = (const float*)d_in[2];
    const float* blead = (const float*)d_in[3];
    const float* w1    = (const float*)d_in[4];
    const float* b1    = (const float*)d_in[5];
    const float* w2    = (const float*)d_in[6];
    const float* b2    = (const float*)d_in[7];
    float* out = (float*)d_out;

    const int N = in_sizes[0] / H128;
    const int E = in_sizes[1] / 2;
    const int NB = (N + BKT - 1) / BKT;
    const int PB = (N + 15) / 16;
    const int* srcs = ei;
    const int* dsts = ei + E;

    char* ws = (char*)d_ws;
    size_t off = 0;
    auto alloc = [&](size_t bytes) {
        void* p = ws + off;
        off = (off + bytes + 255) & ~(size_t)255;
        return p;
    };
    unsigned short* xb    = (unsigned short*)alloc((size_t)N * H128 * 2);
    unsigned short* meanb = (unsigned short*)alloc((size_t)N * H128 * 2);
    unsigned short* hbuf  = (unsigned short*)alloc((size_t)N * H128 * 2);
    double* logits = (double*)alloc((size_t)N * 8);
    int* leader = (int*)alloc((size_t)N * 4);
    int* starts = (int*)alloc((size_t)(N + 1) * 4);
    int* csr    = (int*)alloc((size_t)E * 4);
    unsigned* binned = (unsigned*)alloc((size_t)E * 4);
    int* histg  = (int*)alloc((size_t)NB * NBLK * 4);
    int* bstart = (int*)alloc((size_t)(NB + 1) * 4);
    int* base   = (int*)alloc((size_t)NB * NBLK * 4);
    unsigned short* gwT1 = (unsigned short*)alloc(16384 * 2);
    unsigned short* gwT2 = (unsigned short*)alloc(16384 * 2);

    // fused [bucket histogram | logits+bf16 prep (4 rows/wave) | W transpose]
    k_front<<<NBLK + PB + 2, 256, 0, stream>>>(x, wlead, blead, xb, logits,
                                               dsts, histg, w1, w2, gwT1, gwT2,
                                               N, E, NB, PB);

    // bucket scan + cursors, then binned scatter, then per-bucket CSR
    k_offsets<<<1, MAXNB, 0, stream>>>(histg, bstart, base, NB);
    k_binscatter<<<NBLK, 256, 0, stream>>>(srcs, dsts, base, binned, E, NB);
    k_localize<<<NB, BKT, 0, stream>>>(binned, bstart, starts, csr, N, E, NB);

    // gather-aggregate mean (bf16) + leader election
    k_aggregate<<<(N + 15) / 16, 256, 0, stream>>>(starts, csr, xb, logits, meanb, leader, N);

    // MLP: GEMM1 (mean -> h, gelu, bf16), GEMM2 fused with leader-gather (-> out fp32)
    k_gemm_mfma<<<(N + 127) / 128, 256, 0, stream>>>(meanb, gwT1, b1, nullptr, nullptr, hbuf, N, 1);
    k_gemm_mfma<<<(N + 127) / 128, 256, 0, stream>>>(hbuf, gwT2, b2, leader, out, nullptr, N, 0);
}